// Round 3
// baseline (897.236 us; speedup 1.0000x reference)
//
#include <hip/hip_runtime.h>
#include <hip/hip_bf16.h>
#include <math.h>

#define NN 100000
#define NE 1600000
#define NBLK 391   // ceil(NN/256)
#define ZS 296     // edge_mlp z-buffer row stride bytes (74 words -> ~conflict-free)
#define RS 272     // fused_sage LDS row stride bytes (68 words, 17-bank stride -> <=2-way)
// dims: D_IN = HID = 128, E_CH = 16

typedef __bf16 bf16x8 __attribute__((ext_vector_type(8)));
typedef float f32x4 __attribute__((ext_vector_type(4)));

union BF8 { bf16x8 v; unsigned short u[8]; };

static __device__ __forceinline__ unsigned short f2bf(float f) {
  unsigned int u = __float_as_uint(f);
  unsigned int r = u + 0x7fffu + ((u >> 16) & 1u);   // RNE
  return (unsigned short)(r >> 16);
}
static __device__ __forceinline__ float bf2f(unsigned short b) {
  return __uint_as_float((unsigned int)b << 16);
}
static __device__ __forceinline__ f32x4 zero4() {
  f32x4 z = {0.f, 0.f, 0.f, 0.f}; return z;
}
static __device__ __forceinline__ bf16x8 zerobf8() {
  BF8 t;
  #pragma unroll
  for (int j = 0; j < 8; ++j) t.u[j] = 0;
  return t.v;
}
static __device__ __forceinline__ bf16x8 cvt8(float4 v0, float4 v1, float s) {
  BF8 t;
  t.u[0]=f2bf(v0.x*s); t.u[1]=f2bf(v0.y*s); t.u[2]=f2bf(v0.z*s); t.u[3]=f2bf(v0.w*s);
  t.u[4]=f2bf(v1.x*s); t.u[5]=f2bf(v1.y*s); t.u[6]=f2bf(v1.z*s); t.u[7]=f2bf(v1.w*s);
  return t.v;
}

// ---------------------------------------------------------------------------
// Pre-swizzle weights into MFMA fragment order (bf16):
//   swz[((t*KC + c)*64 + lane)*8 + j] = W[k][n],  k = c*32 + (lane>>4)*8 + j,
//                                                 n = t*16 + (lane&15)
// element regions:
//   [0)      nodeW0 (Wl0|Wr0 stacked, K=256,N=128)   32768
//   [32768)  nodeW1                                   32768
//   [65536)  PQ0 = Wc1 rows   0..127 (K=128,N=128)    16384
//   [81920)  PQ1 = Wc1 rows 128..255 (K=128,N=128)    16384
//   [98304)  Wea = Wc1 rows 256..271 (K=16 pad 32)     4096
//   [102400) Wc2 (K=128,N=64)                          8192
// total 110592
__global__ void prep_swizzle(const float* __restrict__ Wl0, const float* __restrict__ Wr0,
                             const float* __restrict__ Wl1, const float* __restrict__ Wr1,
                             const float* __restrict__ Wc1, const float* __restrict__ Wc2,
                             __hip_bfloat16* __restrict__ swz) {
  int gid = blockIdx.x * 256 + threadIdx.x;
  if (gid >= 110592) return;
  int id = gid;
  const float* A; const float* B = nullptr; int KC, Nc, Ksrc;
  if (id < 32768)        { KC = 8; Nc = 128; Ksrc = 256; A = Wl0; B = Wr0; }
  else if (id < 65536)   { id -= 32768; KC = 8; Nc = 128; Ksrc = 256; A = Wl1; B = Wr1; }
  else if (id < 81920)   { id -= 65536; KC = 4; Nc = 128; Ksrc = 128; A = Wc1; }
  else if (id < 98304)   { id -= 81920; KC = 4; Nc = 128; Ksrc = 128; A = Wc1 + 128 * 128; }
  else if (id < 102400)  { id -= 98304; KC = 1; Nc = 128; Ksrc = 16;  A = Wc1 + 256 * 128; }
  else                   { id -= 102400; KC = 4; Nc = 64;  Ksrc = 128; A = Wc2; }
  int j = id & 7, lane = (id >> 3) & 63, rest = id >> 9;
  int c = rest % KC, t = rest / KC;
  int k = c * 32 + (lane >> 4) * 8 + j;
  int n = t * 16 + (lane & 15);
  float v = 0.f;
  if (k < Ksrc) {
    if (B && k >= 128) v = B[(k - 128) * Nc + n];
    else               v = A[k * Nc + n];
  }
  unsigned short* o = (unsigned short*)swz;
  o[gid] = f2bf(v);
}

// ---------------------------------------------------------------------------
// x (fp32) -> bf16, vectorized
__global__ void x_to_bf16(const float* __restrict__ x, __hip_bfloat16* __restrict__ xb) {
  int i = blockIdx.x * 256 + threadIdx.x;     // one float4 per thread
  float4 v = ((const float4*)x)[i];
  ushort4 p;
  p.x = f2bf(v.x); p.y = f2bf(v.y); p.z = f2bf(v.z); p.w = f2bf(v.w);
  ((ushort4*)xb)[i] = p;
}

// ---------------------------------------------------------------------------
// CSR build: count degrees, scan, fill (src + packed (dst,eid))
__global__ void deg_count(const int* __restrict__ ei, int* __restrict__ degCnt) {
  int e = blockIdx.x * 256 + threadIdx.x;
  atomicAdd(&degCnt[ei[NE + e]], 1);
}

__global__ void scan_block_sums(const int* __restrict__ degCnt, int* __restrict__ blockSums) {
  __shared__ int red[4];
  int i = blockIdx.x * 256 + threadIdx.x;
  int v = (i < NN) ? degCnt[i] : 0;
  #pragma unroll
  for (int off = 32; off; off >>= 1) v += __shfl_down(v, off, 64);
  if ((threadIdx.x & 63) == 0) red[threadIdx.x >> 6] = v;
  __syncthreads();
  if (threadIdx.x == 0) blockSums[blockIdx.x] = red[0] + red[1] + red[2] + red[3];
}

__global__ void scan_partials(const int* __restrict__ blockSums, int* __restrict__ blockOff) {
  __shared__ int lds[512];
  int t = threadIdx.x;
  int v = (t < NBLK) ? blockSums[t] : 0;
  lds[t] = v; __syncthreads();
  #pragma unroll
  for (int off = 1; off < 512; off <<= 1) {
    int a = (t >= off) ? lds[t - off] : 0;
    __syncthreads();
    lds[t] += a;
    __syncthreads();
  }
  if (t < NBLK) blockOff[t] = lds[t] - v;   // exclusive
}

__global__ void scan_write(const int* __restrict__ degCnt, const int* __restrict__ blockOff,
                           int* __restrict__ rowPtr, int* __restrict__ cursor) {
  __shared__ int lds[256];
  int t = threadIdx.x;
  int i = blockIdx.x * 256 + t;
  int v = (i < NN) ? degCnt[i] : 0;
  lds[t] = v; __syncthreads();
  #pragma unroll
  for (int off = 1; off < 256; off <<= 1) {
    int a = (t >= off) ? lds[t - off] : 0;
    __syncthreads();
    lds[t] += a;
    __syncthreads();
  }
  if (i < NN) {
    int excl = blockOff[blockIdx.x] + lds[t] - v;
    rowPtr[i] = excl;
    cursor[i] = excl;
  }
}

__global__ void csr_fill(const int* __restrict__ ei, int* __restrict__ cursor,
                         int* __restrict__ csrSrc, int2* __restrict__ csrDE) {
  int e = blockIdx.x * 256 + threadIdx.x;
  int s = ei[e], d = ei[NE + e];
  int idx = atomicAdd(&cursor[d], 1);
  csrSrc[idx] = s;
  csrDE[idx] = make_int2(d, e);
}

// ---------------------------------------------------------------------------
// fused SAGE layer: per 64-node block
//   phase 1 (gather): msgL[nl] = mean over neighbors of feat[s]   (LDS, bf16)
//   phase 2 (GEMM):   h[n] = relu([msgL | feat[n]] @ [Wl;Wr] + b)
//                     doPQ=0: h -> hOut (global);  doPQ=1: h -> hL (LDS)
//   phase 3 (doPQ=1): P[n] = Wc1a^T h, Q[n] = Wc1b^T h  (from LDS h, no h1 in HBM)
// Removes the msgB HBM round-trip (51.2 MB/layer) and the h1 round-trip + pq_gemm.
__global__ __launch_bounds__(256, 4)
void fused_sage(const __hip_bfloat16* __restrict__ feat,
                const int* __restrict__ csrSrc, const int* __restrict__ rowPtr,
                const int* __restrict__ degCnt,
                const __hip_bfloat16* __restrict__ swzW, const float* __restrict__ bias,
                __hip_bfloat16* __restrict__ hOut,
                int doPQ, const __hip_bfloat16* __restrict__ swzPQ,
                __hip_bfloat16* __restrict__ Pout, __hip_bfloat16* __restrict__ Qout) {
  __shared__ __align__(16) char msgL[64 * RS];
  __shared__ __align__(16) char hL[64 * RS];
  const int tid = threadIdx.x;
  const int nBase = blockIdx.x * 64;

  // ---- phase 1: gather-mean into msgL (16 lanes/node, 16 nodes/round, 4 rounds)
  {
    int g = tid >> 4, c16 = tid & 15;
    for (int r = 0; r < 4; ++r) {
      int nl = r * 16 + g;
      int n = nBase + nl;
      float a[8];
      #pragma unroll
      for (int j = 0; j < 8; ++j) a[j] = 0.f;
      float rinv = 0.f;
      if (n < NN) {
        int rp = rowPtr[n], dg = degCnt[n];
        for (int i = 0; i < dg; i += 4) {
          #pragma unroll
          for (int k = 0; k < 4; ++k) {
            int ii = i + k;
            int s = csrSrc[rp + (ii < dg ? ii : dg - 1)];
            uint4 u = *(const uint4*)((const unsigned short*)feat + (size_t)s * 128 + c16 * 8);
            if (ii < dg) {
              a[0] += bf2f((unsigned short)(u.x & 0xffff)); a[1] += bf2f((unsigned short)(u.x >> 16));
              a[2] += bf2f((unsigned short)(u.y & 0xffff)); a[3] += bf2f((unsigned short)(u.y >> 16));
              a[4] += bf2f((unsigned short)(u.z & 0xffff)); a[5] += bf2f((unsigned short)(u.z >> 16));
              a[6] += bf2f((unsigned short)(u.w & 0xffff)); a[7] += bf2f((unsigned short)(u.w >> 16));
            }
          }
        }
        rinv = 1.f / fmaxf((float)dg, 1.f);
      }
      uint4 p;
      p.x = (unsigned)f2bf(a[0] * rinv) | ((unsigned)f2bf(a[1] * rinv) << 16);
      p.y = (unsigned)f2bf(a[2] * rinv) | ((unsigned)f2bf(a[3] * rinv) << 16);
      p.z = (unsigned)f2bf(a[4] * rinv) | ((unsigned)f2bf(a[5] * rinv) << 16);
      p.w = (unsigned)f2bf(a[6] * rinv) | ((unsigned)f2bf(a[7] * rinv) << 16);
      *(uint4*)(msgL + nl * RS + c16 * 16) = p;
    }
  }
  __syncthreads();

  const int w = tid >> 6, lane = tid & 63;
  const int l15 = lane & 15, quad = lane >> 4;
  int rowg[4];
  #pragma unroll
  for (int nt = 0; nt < 4; ++nt) {
    int n = nBase + nt * 16 + l15;
    rowg[nt] = (n < NN) ? n : (NN - 1);
  }

  // ---- phase 2: node GEMM. wave w covers out-chans [w*32, w*32+32), 64 nodes.
  {
    f32x4 acc[2][4];
    #pragma unroll
    for (int mi = 0; mi < 2; ++mi)
      #pragma unroll
      for (int nt = 0; nt < 4; ++nt) acc[mi][nt] = zero4();

    #pragma unroll
    for (int c = 0; c < 8; ++c) {
      bf16x8 bfr[4];
      if (c < 4) {
        #pragma unroll
        for (int nt = 0; nt < 4; ++nt)
          bfr[nt] = *(const bf16x8*)(msgL + (nt * 16 + l15) * RS + (c * 32 + quad * 8) * 2);
      } else {
        #pragma unroll
        for (int nt = 0; nt < 4; ++nt)
          bfr[nt] = *(const bf16x8*)(feat + (size_t)rowg[nt] * 128 + (c - 4) * 32 + quad * 8);
      }
      #pragma unroll
      for (int mi = 0; mi < 2; ++mi) {
        int mt = w * 2 + mi;
        bf16x8 afr = *(const bf16x8*)(swzW + ((mt * 8 + c) * 64 + lane) * 8);
        #pragma unroll
        for (int nt = 0; nt < 4; ++nt)
          acc[mi][nt] = __builtin_amdgcn_mfma_f32_16x16x32_bf16(afr, bfr[nt], acc[mi][nt], 0, 0, 0);
      }
    }

    #pragma unroll
    for (int mi = 0; mi < 2; ++mi) {
      int mt = w * 2 + mi;
      const int cb = mt * 16 + quad * 4;
      const float4 b4 = *(const float4*)(bias + cb);
      #pragma unroll
      for (int nt = 0; nt < 4; ++nt) {
        ushort4 p;
        p.x = f2bf(fmaxf(acc[mi][nt][0] + b4.x, 0.f));
        p.y = f2bf(fmaxf(acc[mi][nt][1] + b4.y, 0.f));
        p.z = f2bf(fmaxf(acc[mi][nt][2] + b4.z, 0.f));
        p.w = f2bf(fmaxf(acc[mi][nt][3] + b4.w, 0.f));
        if (doPQ) {
          *(ushort4*)(hL + (nt * 16 + l15) * RS + cb * 2) = p;
        } else {
          int n = nBase + nt * 16 + l15;
          if (n < NN)
            *(ushort4*)(hOut + (size_t)n * 128 + cb) = p;
        }
      }
    }
  }

  // ---- phase 3 (layer 1): P/Q GEMM straight from hL. wave w covers 64 of 256
  // stacked out-chans (P:0..127, Q:128..255).
  if (doPQ) {
    __syncthreads();
    f32x4 acc2[4][4];
    #pragma unroll
    for (int mi = 0; mi < 4; ++mi)
      #pragma unroll
      for (int nt = 0; nt < 4; ++nt) acc2[mi][nt] = zero4();

    #pragma unroll
    for (int c = 0; c < 4; ++c) {
      bf16x8 bfr[4];
      #pragma unroll
      for (int nt = 0; nt < 4; ++nt)
        bfr[nt] = *(const bf16x8*)(hL + (nt * 16 + l15) * RS + (c * 32 + quad * 8) * 2);
      #pragma unroll
      for (int mi = 0; mi < 4; ++mi) {
        int mtg = w * 4 + mi;                       // 0..15
        const __hip_bfloat16* base = swzPQ + ((mtg < 8) ? 0 : 16384);
        int t = mtg & 7;
        bf16x8 afr = *(const bf16x8*)(base + ((t * 4 + c) * 64 + lane) * 8);
        #pragma unroll
        for (int nt = 0; nt < 4; ++nt)
          acc2[mi][nt] = __builtin_amdgcn_mfma_f32_16x16x32_bf16(afr, bfr[nt], acc2[mi][nt], 0, 0, 0);
      }
    }

    #pragma unroll
    for (int mi = 0; mi < 4; ++mi) {
      int mtg = w * 4 + mi;
      __hip_bfloat16* outp = (mtg < 8) ? Pout : Qout;
      const int cb = (mtg & 7) * 16 + quad * 4;
      #pragma unroll
      for (int nt = 0; nt < 4; ++nt) {
        int n = nBase + nt * 16 + l15;
        if (n < NN) {
          ushort4 p;
          p.x = f2bf(acc2[mi][nt][0]);
          p.y = f2bf(acc2[mi][nt][1]);
          p.z = f2bf(acc2[mi][nt][2]);
          p.w = f2bf(acc2[mi][nt][3]);
          *(ushort4*)(outp + (size_t)n * 128 + cb) = p;
        }
      }
    }
  }
}

// ---------------------------------------------------------------------------
// edge MLP (CSR order): z1 = relu(P[src]+Q[dst]+Wea^T ea+bc1); z2 = relu(Wc2^T z1+bc2);
// out[eid] = sigmoid(Wc3^T z2 + bc3).
// CSR order: Q[dst] rides L1/L2 (dst-runs of ~16), P[src] random L3-resident gather,
// ea random 64B (cold, unavoidable ~2x line amp), out 4B scatter. Measured best order
// (R0=246us vs eid-order R1=270us): total L2-miss bytes are the binding resource.
// 4 waves x 32 edges/wave, per-wave private LDS z-buffer, no barriers. 4 blocks/CU.
__global__ __launch_bounds__(256, 4)
void edge_mlp(const __hip_bfloat16* __restrict__ P, const __hip_bfloat16* __restrict__ Q,
              const float* __restrict__ ea,
              const int* __restrict__ csrSrc, const int2* __restrict__ csrDE,
              const __hip_bfloat16* __restrict__ swzWea, const __hip_bfloat16* __restrict__ swzWc2,
              const float* __restrict__ Wc3, const float* __restrict__ bc1,
              const float* __restrict__ bc2, const float* __restrict__ bc3,
              float* __restrict__ out) {
  __shared__ char lds[4 * 32 * ZS];   // 37888 B -> 4 blocks/CU
  const int tid = threadIdx.x, w = tid >> 6, lane = tid & 63;
  const int l15 = lane & 15, quad = lane >> 4;
  const int eBase = blockIdx.x * 128 + w * 32;
  char* zbuf = lds + w * (32 * ZS);

  int srcO[2], dstO[2], eid[2];
  #pragma unroll
  for (int t = 0; t < 2; ++t) {
    int p = eBase + t * 16 + l15;
    srcO[t] = csrSrc[p] * 128;
    int2 de = csrDE[p];
    dstO[t] = de.x * 128;
    eid[t] = de.y;
  }

  // ---- prefetch P channel blocks 0..3 (random gather, L3 latency) ASAP
  ushort4 pA[2][4];
  #pragma unroll
  for (int nt = 0; nt < 2; ++nt)
    #pragma unroll
    for (int mt = 0; mt < 4; ++mt)
      pA[nt][mt] = *(const ushort4*)(P + srcO[nt] + mt * 16 + quad * 4);

  // ---- ea -> bf16 B fragments (K=16 zero-padded to 32)
  bf16x8 bfr[2];
  #pragma unroll
  for (int nt = 0; nt < 2; ++nt) {
    if (quad < 2) {
      const float4* pe = (const float4*)(ea + (size_t)eid[nt] * 16 + quad * 8);
      bfr[nt] = cvt8(pe[0], pe[1], 1.f);
    } else {
      bfr[nt] = zerobf8();
    }
  }

  // ---- layer 1 MFMA, half A (channel blocks 0..3)
  f32x4 acc[4][2];
  #pragma unroll
  for (int mt = 0; mt < 4; ++mt)
    #pragma unroll
    for (int nt = 0; nt < 2; ++nt) acc[mt][nt] = zero4();
  #pragma unroll
  for (int mt = 0; mt < 4; ++mt) {
    bf16x8 afr = *(const bf16x8*)(swzWea + (mt * 64 + lane) * 8);
    #pragma unroll
    for (int nt = 0; nt < 2; ++nt)
      acc[mt][nt] = __builtin_amdgcn_mfma_f32_16x16x32_bf16(afr, bfr[nt], acc[mt][nt], 0, 0, 0);
  }

  // ---- prefetch P blocks 4..7 and Q blocks 0..3 (consumed next phase)
  ushort4 pB[2][4], qA[2][4];
  #pragma unroll
  for (int nt = 0; nt < 2; ++nt)
    #pragma unroll
    for (int mt = 0; mt < 4; ++mt)
      pB[nt][mt] = *(const ushort4*)(P + srcO[nt] + (mt + 4) * 16 + quad * 4);
  #pragma unroll
  for (int nt = 0; nt < 2; ++nt)
    #pragma unroll
    for (int mt = 0; mt < 4; ++mt)
      qA[nt][mt] = *(const ushort4*)(Q + dstO[nt] + mt * 16 + quad * 4);

  // ---- epilogue 1, half A: z1 = relu(acc + P + Q + bc1) -> LDS (bf16, stride ZS)
  #pragma unroll
  for (int mt = 0; mt < 4; ++mt) {
    const int cb = mt * 16 + quad * 4;
    const float4 b4 = *(const float4*)(bc1 + cb);
    #pragma unroll
    for (int nt = 0; nt < 2; ++nt) {
      ushort4 pu = pA[nt][mt];
      ushort4 qu = qA[nt][mt];
      int er = nt * 16 + l15;
      ushort4 z;
      z.x = f2bf(fmaxf(acc[mt][nt][0] + bf2f(pu.x) + bf2f(qu.x) + b4.x, 0.f));
      z.y = f2bf(fmaxf(acc[mt][nt][1] + bf2f(pu.y) + bf2f(qu.y) + b4.y, 0.f));
      z.z = f2bf(fmaxf(acc[mt][nt][2] + bf2f(pu.z) + bf2f(qu.z) + b4.z, 0.f));
      z.w = f2bf(fmaxf(acc[mt][nt][3] + bf2f(pu.w) + bf2f(qu.w) + b4.w, 0.f));
      *(ushort4*)(zbuf + er * ZS + cb * 2) = z;
    }
  }

  // ---- layer 1 MFMA, half B (channel blocks 4..7; bfr still live, acc reused)
  #pragma unroll
  for (int mt = 0; mt < 4; ++mt)
    #pragma unroll
    for (int nt = 0; nt < 2; ++nt) acc[mt][nt] = zero4();
  #pragma unroll
  for (int mt = 0; mt < 4; ++mt) {
    bf16x8 afr = *(const bf16x8*)(swzWea + ((mt + 4) * 64 + lane) * 8);
    #pragma unroll
    for (int nt = 0; nt < 2; ++nt)
      acc[mt][nt] = __builtin_amdgcn_mfma_f32_16x16x32_bf16(afr, bfr[nt], acc[mt][nt], 0, 0, 0);
  }

  // ---- prefetch Q blocks 4..7
  ushort4 qB[2][4];
  #pragma unroll
  for (int nt = 0; nt < 2; ++nt)
    #pragma unroll
    for (int mt = 0; mt < 4; ++mt)
      qB[nt][mt] = *(const ushort4*)(Q + dstO[nt] + (mt + 4) * 16 + quad * 4);

  // ---- epilogue 1, half B
  #pragma unroll
  for (int mt = 0; mt < 4; ++mt) {
    const int cb = (mt + 4) * 16 + quad * 4;
    const float4 b4 = *(const float4*)(bc1 + cb);
    #pragma unroll
    for (int nt = 0; nt < 2; ++nt) {
      ushort4 pu = pB[nt][mt];
      ushort4 qu = qB[nt][mt];
      int er = nt * 16 + l15;
      ushort4 z;
      z.x = f2bf(fmaxf(acc[mt][nt][0] + bf2f(pu.x) + bf2f(qu.x) + b4.x, 0.f));
      z.y = f2bf(fmaxf(acc[mt][nt][1] + bf2f(pu.y) + bf2f(qu.y) + b4.y, 0.f));
      z.z = f2bf(fmaxf(acc[mt][nt][2] + bf2f(pu.z) + bf2f(qu.z) + b4.z, 0.f));
      z.w = f2bf(fmaxf(acc[mt][nt][3] + bf2f(pu.w) + bf2f(qu.w) + b4.w, 0.f));
      *(ushort4*)(zbuf + er * ZS + cb * 2) = z;
    }
  }

  // ---- layer 2: z2^T = Wc2^T @ z1^T  (K=128, 64 out chans)
  f32x4 acc2[4][2];
  #pragma unroll
  for (int mt = 0; mt < 4; ++mt)
    #pragma unroll
    for (int nt = 0; nt < 2; ++nt) acc2[mt][nt] = zero4();

  #pragma unroll
  for (int c = 0; c < 4; ++c) {
    bf16x8 b2[2];
    #pragma unroll
    for (int nt = 0; nt < 2; ++nt)
      b2[nt] = *(const bf16x8*)(zbuf + (nt * 16 + l15) * ZS + (c * 32 + quad * 8) * 2);
    #pragma unroll
    for (int mt = 0; mt < 4; ++mt) {
      bf16x8 afr = *(const bf16x8*)(swzWc2 + ((mt * 4 + c) * 64 + lane) * 8);
      #pragma unroll
      for (int nt = 0; nt < 2; ++nt)
        acc2[mt][nt] = __builtin_amdgcn_mfma_f32_16x16x32_bf16(afr, b2[nt], acc2[mt][nt], 0, 0, 0);
    }
  }

  // ---- epilogue 2: z2 -> LDS rows (bf16, 64 chans, same stride; z1 reads done)
  #pragma unroll
  for (int mt = 0; mt < 4; ++mt) {
    const int cb = mt * 16 + quad * 4;
    const float4 b4 = *(const float4*)(bc2 + cb);
    #pragma unroll
    for (int nt = 0; nt < 2; ++nt) {
      int er = nt * 16 + l15;
      ushort4 z;
      z.x = f2bf(fmaxf(acc2[mt][nt][0] + b4.x, 0.f));
      z.y = f2bf(fmaxf(acc2[mt][nt][1] + b4.y, 0.f));
      z.z = f2bf(fmaxf(acc2[mt][nt][2] + b4.z, 0.f));
      z.w = f2bf(fmaxf(acc2[mt][nt][3] + b4.w, 0.f));
      *(ushort4*)(zbuf + er * ZS + cb * 2) = z;
    }
  }

  // ---- layer 3: lane pair per edge (half-wave split over 64 chans), sigmoid, scatter
  {
    int e = lane & 31, half = lane >> 5;
    float a3 = (half == 0) ? bc3[0] : 0.f;
    #pragma unroll
    for (int k2 = 0; k2 < 16; ++k2) {
      unsigned int u = *(const unsigned int*)(zbuf + e * ZS + half * 64 + k2 * 4);
      float v0 = __uint_as_float(u << 16);
      float v1 = __uint_as_float(u & 0xffff0000u);
      const float2 wv = *(const float2*)(Wc3 + half * 32 + 2 * k2);
      a3 += v0 * wv.x + v1 * wv.y;
    }
    a3 += __shfl_xor(a3, 32);
    if (half == 0) {
      int oe = csrDE[eBase + e].y;
      out[oe] = 1.f / (1.f + __expf(-a3));
    }
  }
}

// ---------------------------------------------------------------------------
extern "C" void kernel_launch(void* const* d_in, const int* in_sizes, int n_in,
                              void* d_out, int out_size, void* d_ws, size_t ws_size,
                              hipStream_t stream) {
  const float* x   = (const float*)d_in[0];
  const int*   ei  = (const int*)d_in[1];
  const float* ea  = (const float*)d_in[2];
  const float* Wl0 = (const float*)d_in[3];
  const float* Wr0 = (const float*)d_in[4];
  const float* b0  = (const float*)d_in[5];
  const float* Wl1 = (const float*)d_in[6];
  const float* Wr1 = (const float*)d_in[7];
  const float* b1  = (const float*)d_in[8];
  const float* Wc1 = (const float*)d_in[9];
  const float* bc1 = (const float*)d_in[10];
  const float* Wc2 = (const float*)d_in[11];
  const float* bc2 = (const float*)d_in[12];
  const float* Wc3 = (const float*)d_in[13];
  const float* bc3 = (const float*)d_in[14];
  float* out = (float*)d_out;

  char* ws = (char*)d_ws;
  int* degCnt    = (int*)(ws + 0);                            //    400,000 B
  int* rowPtr    = (int*)(ws + 400000);                       //    400,000 B
  int* cursor    = (int*)(ws + 800000);                       //    400,000 B
  int* blockSums = (int*)(ws + 1200000);                      //      2,048 B
  int* blockOff  = (int*)(ws + 1202048);                      //      2,048 B
  int* csrSrc    = (int*)(ws + 1204096);                      //  6,400,000 B
  int2* csrDE    = (int2*)(ws + 7604096);                     // 12,800,000 B
  __hip_bfloat16* bufB = (__hip_bfloat16*)(ws + 20404096);    // 25,600,000 B  P
  __hip_bfloat16* bufC = (__hip_bfloat16*)(ws + 46004096);    // 25,600,000 B  h0
  __hip_bfloat16* bufD = (__hip_bfloat16*)(ws + 71604096);    // 25,600,000 B  xb / Q
  __hip_bfloat16* swz  = (__hip_bfloat16*)(ws + 97204096);    //    221,184 B
  // total 97,425,280 B (unchanged from proven layout)
  __hip_bfloat16* Pb  = bufB;
  __hip_bfloat16* h0b = bufC;
  __hip_bfloat16* xb  = bufD;
  __hip_bfloat16* Qb  = bufD;   // xb dead after fused layer 0; Q written in layer 1

  hipMemsetAsync(degCnt, 0, 400000, stream);
  prep_swizzle<<<432, 256, 0, stream>>>(Wl0, Wr0, Wl1, Wr1, Wc1, Wc2, swz);
  x_to_bf16<<<12500, 256, 0, stream>>>(x, xb);

  // CSR build (dst-sorted edge order; gathers + edge classifier)
  deg_count<<<NE / 256, 256, 0, stream>>>(ei, degCnt);
  scan_block_sums<<<NBLK, 256, 0, stream>>>(degCnt, blockSums);
  scan_partials<<<1, 512, 0, stream>>>(blockSums, blockOff);
  scan_write<<<NBLK, 256, 0, stream>>>(degCnt, blockOff, rowPtr, cursor);
  csr_fill<<<NE / 256, 256, 0, stream>>>(ei, cursor, csrSrc, csrDE);

  // layer 0: fused gather + node GEMM  (h0 = relu([mean(xb)|xb]W0+b0))
  fused_sage<<<1563, 256, 0, stream>>>(xb, csrSrc, rowPtr, degCnt, swz, b0, h0b,
                                       0, nullptr, nullptr, nullptr);
  // layer 1: fused gather + node GEMM + P/Q GEMM (h1 never hits HBM)
  fused_sage<<<1563, 256, 0, stream>>>(h0b, csrSrc, rowPtr, degCnt, swz + 32768, b1, nullptr,
                                       1, swz + 65536, Pb, Qb);

  // per-edge MLP in CSR order
  edge_mlp<<<NE / 128, 256, 0, stream>>>(Pb, Qb, ea, csrSrc, csrDE,
                                         swz + 98304, swz + 102400,
                                         Wc3, bc1, bc2, bc3, out);
}

// Round 4
// 842.393 us; speedup vs baseline: 1.0651x; 1.0651x over previous
//
#include <hip/hip_runtime.h>
#include <hip/hip_bf16.h>
#include <math.h>

#define NN 100000
#define NE 1600000
#define NBLK 391   // ceil(NN/256)
#define ZS 296     // LDS row stride bytes (74 words, bank-shift 10 -> measured conflict-free)
// dims: D_IN = HID = 128, E_CH = 16

typedef __bf16 bf16x8 __attribute__((ext_vector_type(8)));
typedef float f32x4 __attribute__((ext_vector_type(4)));

union BF8 { bf16x8 v; unsigned short u[8]; };

static __device__ __forceinline__ unsigned short f2bf(float f) {
  unsigned int u = __float_as_uint(f);
  unsigned int r = u + 0x7fffu + ((u >> 16) & 1u);   // RNE
  return (unsigned short)(r >> 16);
}
static __device__ __forceinline__ float bf2f(unsigned short b) {
  return __uint_as_float((unsigned int)b << 16);
}
static __device__ __forceinline__ f32x4 zero4() {
  f32x4 z = {0.f, 0.f, 0.f, 0.f}; return z;
}
static __device__ __forceinline__ bf16x8 zerobf8() {
  BF8 t;
  #pragma unroll
  for (int j = 0; j < 8; ++j) t.u[j] = 0;
  return t.v;
}
static __device__ __forceinline__ bf16x8 cvt8(float4 v0, float4 v1, float s) {
  BF8 t;
  t.u[0]=f2bf(v0.x*s); t.u[1]=f2bf(v0.y*s); t.u[2]=f2bf(v0.z*s); t.u[3]=f2bf(v0.w*s);
  t.u[4]=f2bf(v1.x*s); t.u[5]=f2bf(v1.y*s); t.u[6]=f2bf(v1.z*s); t.u[7]=f2bf(v1.w*s);
  return t.v;
}

// ---------------------------------------------------------------------------
// Pre-swizzle weights into MFMA fragment order (bf16):
//   swz[((t*KC + c)*64 + lane)*8 + j] = W[k][n],  k = c*32 + (lane>>4)*8 + j,
//                                                 n = t*16 + (lane&15)
// element regions:
//   [0)      nodeW0 (Wl0|Wr0 stacked, K=256,N=128)   32768
//   [32768)  nodeW1                                   32768
//   [65536)  PQ0 = Wc1 rows   0..127 (K=128,N=128)    16384
//   [81920)  PQ1 = Wc1 rows 128..255 (K=128,N=128)    16384
//   [98304)  Wea = Wc1 rows 256..271 (K=16 pad 32)     4096
//   [102400) Wc2 (K=128,N=64)                          8192
// total 110592
__global__ void prep_swizzle(const float* __restrict__ Wl0, const float* __restrict__ Wr0,
                             const float* __restrict__ Wl1, const float* __restrict__ Wr1,
                             const float* __restrict__ Wc1, const float* __restrict__ Wc2,
                             __hip_bfloat16* __restrict__ swz) {
  int gid = blockIdx.x * 256 + threadIdx.x;
  if (gid >= 110592) return;
  int id = gid;
  const float* A; const float* B = nullptr; int KC, Nc, Ksrc;
  if (id < 32768)        { KC = 8; Nc = 128; Ksrc = 256; A = Wl0; B = Wr0; }
  else if (id < 65536)   { id -= 32768; KC = 8; Nc = 128; Ksrc = 256; A = Wl1; B = Wr1; }
  else if (id < 81920)   { id -= 65536; KC = 4; Nc = 128; Ksrc = 128; A = Wc1; }
  else if (id < 98304)   { id -= 81920; KC = 4; Nc = 128; Ksrc = 128; A = Wc1 + 128 * 128; }
  else if (id < 102400)  { id -= 98304; KC = 1; Nc = 128; Ksrc = 16;  A = Wc1 + 256 * 128; }
  else                   { id -= 102400; KC = 4; Nc = 64;  Ksrc = 128; A = Wc2; }
  int j = id & 7, lane = (id >> 3) & 63, rest = id >> 9;
  int c = rest % KC, t = rest / KC;
  int k = c * 32 + (lane >> 4) * 8 + j;
  int n = t * 16 + (lane & 15);
  float v = 0.f;
  if (k < Ksrc) {
    if (B && k >= 128) v = B[(k - 128) * Nc + n];
    else               v = A[k * Nc + n];
  }
  unsigned short* o = (unsigned short*)swz;
  o[gid] = f2bf(v);
}

// ---------------------------------------------------------------------------
// x (fp32) -> bf16, vectorized
__global__ void x_to_bf16(const float* __restrict__ x, __hip_bfloat16* __restrict__ xb) {
  int i = blockIdx.x * 256 + threadIdx.x;     // one float4 per thread
  float4 v = ((const float4*)x)[i];
  ushort4 p;
  p.x = f2bf(v.x); p.y = f2bf(v.y); p.z = f2bf(v.z); p.w = f2bf(v.w);
  ((ushort4*)xb)[i] = p;
}

// ---------------------------------------------------------------------------
// CSR build: count degrees, scan, fill (src + packed (dst,eid))
__global__ void deg_count(const int* __restrict__ ei, int* __restrict__ degCnt) {
  int e = blockIdx.x * 256 + threadIdx.x;
  atomicAdd(&degCnt[ei[NE + e]], 1);
}

__global__ void scan_block_sums(const int* __restrict__ degCnt, int* __restrict__ blockSums) {
  __shared__ int red[4];
  int i = blockIdx.x * 256 + threadIdx.x;
  int v = (i < NN) ? degCnt[i] : 0;
  #pragma unroll
  for (int off = 32; off; off >>= 1) v += __shfl_down(v, off, 64);
  if ((threadIdx.x & 63) == 0) red[threadIdx.x >> 6] = v;
  __syncthreads();
  if (threadIdx.x == 0) blockSums[blockIdx.x] = red[0] + red[1] + red[2] + red[3];
}

__global__ void scan_partials(const int* __restrict__ blockSums, int* __restrict__ blockOff) {
  __shared__ int lds[512];
  int t = threadIdx.x;
  int v = (t < NBLK) ? blockSums[t] : 0;
  lds[t] = v; __syncthreads();
  #pragma unroll
  for (int off = 1; off < 512; off <<= 1) {
    int a = (t >= off) ? lds[t - off] : 0;
    __syncthreads();
    lds[t] += a;
    __syncthreads();
  }
  if (t < NBLK) blockOff[t] = lds[t] - v;   // exclusive
}

__global__ void scan_write(const int* __restrict__ degCnt, const int* __restrict__ blockOff,
                           int* __restrict__ rowPtr, int* __restrict__ cursor) {
  __shared__ int lds[256];
  int t = threadIdx.x;
  int i = blockIdx.x * 256 + t;
  int v = (i < NN) ? degCnt[i] : 0;
  lds[t] = v; __syncthreads();
  #pragma unroll
  for (int off = 1; off < 256; off <<= 1) {
    int a = (t >= off) ? lds[t - off] : 0;
    __syncthreads();
    lds[t] += a;
    __syncthreads();
  }
  if (i < NN) {
    int excl = blockOff[blockIdx.x] + lds[t] - v;
    rowPtr[i] = excl;
    cursor[i] = excl;
  }
}

__global__ void csr_fill(const int* __restrict__ ei, int* __restrict__ cursor,
                         int* __restrict__ csrSrc, int2* __restrict__ csrDE) {
  int e = blockIdx.x * 256 + threadIdx.x;
  int s = ei[e], d = ei[NE + e];
  int idx = atomicAdd(&cursor[d], 1);
  csrSrc[idx] = s;
  csrDE[idx] = make_int2(d, e);
}

// ---------------------------------------------------------------------------
// gather-mean: msgOut[n] = mean over neighbors s of feat[s]  (bf16 in/out)
// 16 lanes per node (16B each = full 256B row), 16 nodes/block, unroll-4 for MLP.
// Kept standalone and barrier-free: the random gather is latency-bound and needs
// maximal TLP (R3 lesson: fusing it with barrier'd GEMM collapsed occupancy to 8%).
__global__ __launch_bounds__(256, 8)
void gather_agg(const __hip_bfloat16* __restrict__ xb,
                const int* __restrict__ csrSrc, const int* __restrict__ rowPtr,
                const int* __restrict__ degCnt, __hip_bfloat16* __restrict__ msgOut) {
  int g = threadIdx.x >> 4, c16 = threadIdx.x & 15;
  int n = blockIdx.x * 16 + g;             // grid 6250 x 16 = 100000 exact
  int rp = rowPtr[n], dg = degCnt[n];
  float a[8];
  #pragma unroll
  for (int j = 0; j < 8; ++j) a[j] = 0.f;
  for (int i = 0; i < dg; i += 4) {
    #pragma unroll
    for (int k = 0; k < 4; ++k) {
      int ii = i + k;
      int s = csrSrc[rp + (ii < dg ? ii : dg - 1)];
      uint4 u = *(const uint4*)((const unsigned short*)xb + (size_t)s * 128 + c16 * 8);
      if (ii < dg) {
        a[0] += bf2f((unsigned short)(u.x & 0xffff)); a[1] += bf2f((unsigned short)(u.x >> 16));
        a[2] += bf2f((unsigned short)(u.y & 0xffff)); a[3] += bf2f((unsigned short)(u.y >> 16));
        a[4] += bf2f((unsigned short)(u.z & 0xffff)); a[5] += bf2f((unsigned short)(u.z >> 16));
        a[6] += bf2f((unsigned short)(u.w & 0xffff)); a[7] += bf2f((unsigned short)(u.w >> 16));
      }
    }
  }
  float r = 1.f / fmaxf((float)dg, 1.f);
  uint4 p;
  p.x = (unsigned)f2bf(a[0] * r) | ((unsigned)f2bf(a[1] * r) << 16);
  p.y = (unsigned)f2bf(a[2] * r) | ((unsigned)f2bf(a[3] * r) << 16);
  p.z = (unsigned)f2bf(a[4] * r) | ((unsigned)f2bf(a[5] * r) << 16);
  p.w = (unsigned)f2bf(a[6] * r) | ((unsigned)f2bf(a[7] * r) << 16);
  *(uint4*)((unsigned short*)msgOut + (size_t)n * 128 + c16 * 8) = p;
}

// ---------------------------------------------------------------------------
// node GEMM (layer 0): h[n] = relu([mean | self[n]] @ [Wl;Wr] + b)   -> bf16 out
__global__ __launch_bounds__(256, 2)
void node_gemm(const __hip_bfloat16* __restrict__ msgB,
               const __hip_bfloat16* __restrict__ selfB16,
               const __hip_bfloat16* __restrict__ swzW, const float* __restrict__ bias,
               __hip_bfloat16* __restrict__ hOut) {
  const int tid = threadIdx.x, w = tid >> 6, lane = tid & 63;
  const int l15 = lane & 15, quad = lane >> 4;
  const int nBase = blockIdx.x * 256 + w * 64;

  int row[4];
  #pragma unroll
  for (int t = 0; t < 4; ++t) {
    int n = nBase + t * 16 + l15;
    if (n > NN - 1) n = NN - 1;
    row[t] = n;
  }

  f32x4 acc[8][4];
  #pragma unroll
  for (int mt = 0; mt < 8; ++mt)
    #pragma unroll
    for (int nt = 0; nt < 4; ++nt) acc[mt][nt] = zero4();

  #pragma unroll
  for (int c = 0; c < 8; ++c) {
    bf16x8 bfr[4];
    if (c < 4) {
      #pragma unroll
      for (int nt = 0; nt < 4; ++nt)
        bfr[nt] = *(const bf16x8*)(msgB + (size_t)row[nt] * 128 + c * 32 + quad * 8);
    } else {
      #pragma unroll
      for (int nt = 0; nt < 4; ++nt)
        bfr[nt] = *(const bf16x8*)(selfB16 + (size_t)row[nt] * 128 + (c - 4) * 32 + quad * 8);
    }
    bf16x8 afr[8];
    #pragma unroll
    for (int mt = 0; mt < 8; ++mt)
      afr[mt] = *(const bf16x8*)(swzW + ((mt * 8 + c) * 64 + lane) * 8);
    #pragma unroll
    for (int mt = 0; mt < 8; ++mt)
      #pragma unroll
      for (int nt = 0; nt < 4; ++nt)
        acc[mt][nt] = __builtin_amdgcn_mfma_f32_16x16x32_bf16(afr[mt], bfr[nt], acc[mt][nt], 0, 0, 0);
  }

  #pragma unroll
  for (int mt = 0; mt < 8; ++mt) {
    const float4 b4 = *(const float4*)(bias + mt * 16 + quad * 4);
    #pragma unroll
    for (int nt = 0; nt < 4; ++nt) {
      int n = nBase + nt * 16 + l15;
      if (n < NN) {
        ushort4 p;
        p.x = f2bf(fmaxf(acc[mt][nt][0] + b4.x, 0.f));
        p.y = f2bf(fmaxf(acc[mt][nt][1] + b4.y, 0.f));
        p.z = f2bf(fmaxf(acc[mt][nt][2] + b4.z, 0.f));
        p.w = f2bf(fmaxf(acc[mt][nt][3] + b4.w, 0.f));
        *(ushort4*)(hOut + (size_t)n * 128 + mt * 16 + quad * 4) = p;
      }
    }
  }
}

// ---------------------------------------------------------------------------
// node GEMM + P/Q GEMM fused (layer 1): dense->dense fusion only (no gather, no
// barrier, no occupancy change). h1 = relu([mean|self]W1+b1) -> wave-private LDS ->
// P = Wc1a^T h1, Q = Wc1b^T h1. Eliminates the h1 HBM round-trip (51.2 MB) and the
// separate pq_gemm launch.
// NOTE: Pout may alias msgB — each block reads only its own 256 msgB rows (phase A)
// before writing the same rows as P (phase B); blocks are row-disjoint.
__global__ __launch_bounds__(256, 2)
void node_pq_gemm(const __hip_bfloat16* __restrict__ msgB,
                  const __hip_bfloat16* __restrict__ selfB16,
                  const __hip_bfloat16* __restrict__ swzW, const float* __restrict__ bias,
                  const __hip_bfloat16* __restrict__ swzPQ,
                  __hip_bfloat16* __restrict__ Pout, __hip_bfloat16* __restrict__ Qout) {
  __shared__ __align__(16) char hLds[4 * 64 * ZS];   // 75776 B -> 2 blocks/CU
  const int tid = threadIdx.x, w = tid >> 6, lane = tid & 63;
  const int l15 = lane & 15, quad = lane >> 4;
  const int nBase = blockIdx.x * 256 + w * 64;
  char* hbuf = hLds + w * (64 * ZS);

  int row[4];
  #pragma unroll
  for (int t = 0; t < 4; ++t) {
    int n = nBase + t * 16 + l15;
    if (n > NN - 1) n = NN - 1;
    row[t] = n;
  }

  // ---- phase A: node GEMM, relu -> hbuf (LDS, bf16, stride ZS)
  {
    f32x4 acc[8][4];
    #pragma unroll
    for (int mt = 0; mt < 8; ++mt)
      #pragma unroll
      for (int nt = 0; nt < 4; ++nt) acc[mt][nt] = zero4();

    #pragma unroll
    for (int c = 0; c < 8; ++c) {
      bf16x8 bfr[4];
      if (c < 4) {
        #pragma unroll
        for (int nt = 0; nt < 4; ++nt)
          bfr[nt] = *(const bf16x8*)(msgB + (size_t)row[nt] * 128 + c * 32 + quad * 8);
      } else {
        #pragma unroll
        for (int nt = 0; nt < 4; ++nt)
          bfr[nt] = *(const bf16x8*)(selfB16 + (size_t)row[nt] * 128 + (c - 4) * 32 + quad * 8);
      }
      bf16x8 afr[8];
      #pragma unroll
      for (int mt = 0; mt < 8; ++mt)
        afr[mt] = *(const bf16x8*)(swzW + ((mt * 8 + c) * 64 + lane) * 8);
      #pragma unroll
      for (int mt = 0; mt < 8; ++mt)
        #pragma unroll
        for (int nt = 0; nt < 4; ++nt)
          acc[mt][nt] = __builtin_amdgcn_mfma_f32_16x16x32_bf16(afr[mt], bfr[nt], acc[mt][nt], 0, 0, 0);
    }

    #pragma unroll
    for (int mt = 0; mt < 8; ++mt) {
      const int cb = mt * 16 + quad * 4;
      const float4 b4 = *(const float4*)(bias + cb);
      #pragma unroll
      for (int nt = 0; nt < 4; ++nt) {
        ushort4 p;
        p.x = f2bf(fmaxf(acc[mt][nt][0] + b4.x, 0.f));
        p.y = f2bf(fmaxf(acc[mt][nt][1] + b4.y, 0.f));
        p.z = f2bf(fmaxf(acc[mt][nt][2] + b4.z, 0.f));
        p.w = f2bf(fmaxf(acc[mt][nt][3] + b4.w, 0.f));
        *(ushort4*)(hbuf + (nt * 16 + l15) * ZS + cb * 2) = p;
      }
    }
  }

  // ---- phase B: P (hf=0) then Q (hf=1), K=128 from hbuf (wave-private: no barrier)
  for (int hf = 0; hf < 2; ++hf) {
    const __hip_bfloat16* swzH = swzPQ + hf * 16384;
    __hip_bfloat16* outp = hf ? Qout : Pout;
    f32x4 acc2[8][4];
    #pragma unroll
    for (int mt = 0; mt < 8; ++mt)
      #pragma unroll
      for (int nt = 0; nt < 4; ++nt) acc2[mt][nt] = zero4();

    #pragma unroll
    for (int c = 0; c < 4; ++c) {
      bf16x8 bfr[4];
      #pragma unroll
      for (int nt = 0; nt < 4; ++nt)
        bfr[nt] = *(const bf16x8*)(hbuf + (nt * 16 + l15) * ZS + (c * 32 + quad * 8) * 2);
      bf16x8 afr[8];
      #pragma unroll
      for (int mt = 0; mt < 8; ++mt)
        afr[mt] = *(const bf16x8*)(swzH + ((mt * 4 + c) * 64 + lane) * 8);
      #pragma unroll
      for (int mt = 0; mt < 8; ++mt)
        #pragma unroll
        for (int nt = 0; nt < 4; ++nt)
          acc2[mt][nt] = __builtin_amdgcn_mfma_f32_16x16x32_bf16(afr[mt], bfr[nt], acc2[mt][nt], 0, 0, 0);
    }

    #pragma unroll
    for (int mt = 0; mt < 8; ++mt) {
      #pragma unroll
      for (int nt = 0; nt < 4; ++nt) {
        int n = nBase + nt * 16 + l15;
        if (n < NN) {
          ushort4 p;
          p.x = f2bf(acc2[mt][nt][0]);
          p.y = f2bf(acc2[mt][nt][1]);
          p.z = f2bf(acc2[mt][nt][2]);
          p.w = f2bf(acc2[mt][nt][3]);
          *(ushort4*)(outp + (size_t)n * 128 + mt * 16 + quad * 4) = p;
        }
      }
    }
  }
}

// ---------------------------------------------------------------------------
// edge MLP (CSR order): z1 = relu(P[src]+Q[dst]+Wea^T ea+bc1); z2 = relu(Wc2^T z1+bc2);
// out[eid] = sigmoid(Wc3^T z2 + bc3).
// CSR order measured best (R0 246us vs eid-order R1 270us): total L2-miss bytes are
// the binding resource; Q[dst] rides L1/L2 via dst-runs.
// 4 waves x 32 edges/wave, per-wave private LDS z-buffer, no barriers. 4 blocks/CU.
__global__ __launch_bounds__(256, 4)
void edge_mlp(const __hip_bfloat16* __restrict__ P, const __hip_bfloat16* __restrict__ Q,
              const float* __restrict__ ea,
              const int* __restrict__ csrSrc, const int2* __restrict__ csrDE,
              const __hip_bfloat16* __restrict__ swzWea, const __hip_bfloat16* __restrict__ swzWc2,
              const float* __restrict__ Wc3, const float* __restrict__ bc1,
              const float* __restrict__ bc2, const float* __restrict__ bc3,
              float* __restrict__ out) {
  __shared__ char lds[4 * 32 * ZS];   // 37888 B -> 4 blocks/CU
  const int tid = threadIdx.x, w = tid >> 6, lane = tid & 63;
  const int l15 = lane & 15, quad = lane >> 4;
  const int eBase = blockIdx.x * 128 + w * 32;
  char* zbuf = lds + w * (32 * ZS);

  int srcO[2], dstO[2], eid[2];
  #pragma unroll
  for (int t = 0; t < 2; ++t) {
    int p = eBase + t * 16 + l15;
    srcO[t] = csrSrc[p] * 128;
    int2 de = csrDE[p];
    dstO[t] = de.x * 128;
    eid[t] = de.y;
  }

  // ---- prefetch P channel blocks 0..3 (random gather, L3 latency) ASAP
  ushort4 pA[2][4];
  #pragma unroll
  for (int nt = 0; nt < 2; ++nt)
    #pragma unroll
    for (int mt = 0; mt < 4; ++mt)
      pA[nt][mt] = *(const ushort4*)(P + srcO[nt] + mt * 16 + quad * 4);

  // ---- ea -> bf16 B fragments (K=16 zero-padded to 32)
  bf16x8 bfr[2];
  #pragma unroll
  for (int nt = 0; nt < 2; ++nt) {
    if (quad < 2) {
      const float4* pe = (const float4*)(ea + (size_t)eid[nt] * 16 + quad * 8);
      bfr[nt] = cvt8(pe[0], pe[1], 1.f);
    } else {
      bfr[nt] = zerobf8();
    }
  }

  // ---- layer 1 MFMA, half A (channel blocks 0..3)
  f32x4 acc[4][2];
  #pragma unroll
  for (int mt = 0; mt < 4; ++mt)
    #pragma unroll
    for (int nt = 0; nt < 2; ++nt) acc[mt][nt] = zero4();
  #pragma unroll
  for (int mt = 0; mt < 4; ++mt) {
    bf16x8 afr = *(const bf16x8*)(swzWea + (mt * 64 + lane) * 8);
    #pragma unroll
    for (int nt = 0; nt < 2; ++nt)
      acc[mt][nt] = __builtin_amdgcn_mfma_f32_16x16x32_bf16(afr, bfr[nt], acc[mt][nt], 0, 0, 0);
  }

  // ---- prefetch P blocks 4..7 and Q blocks 0..3 (consumed next phase)
  ushort4 pB[2][4], qA[2][4];
  #pragma unroll
  for (int nt = 0; nt < 2; ++nt)
    #pragma unroll
    for (int mt = 0; mt < 4; ++mt)
      pB[nt][mt] = *(const ushort4*)(P + srcO[nt] + (mt + 4) * 16 + quad * 4);
  #pragma unroll
  for (int nt = 0; nt < 2; ++nt)
    #pragma unroll
    for (int mt = 0; mt < 4; ++mt)
      qA[nt][mt] = *(const ushort4*)(Q + dstO[nt] + mt * 16 + quad * 4);

  // ---- epilogue 1, half A: z1 = relu(acc + P + Q + bc1) -> LDS (bf16, stride ZS)
  #pragma unroll
  for (int mt = 0; mt < 4; ++mt) {
    const int cb = mt * 16 + quad * 4;
    const float4 b4 = *(const float4*)(bc1 + cb);
    #pragma unroll
    for (int nt = 0; nt < 2; ++nt) {
      ushort4 pu = pA[nt][mt];
      ushort4 qu = qA[nt][mt];
      int er = nt * 16 + l15;
      ushort4 z;
      z.x = f2bf(fmaxf(acc[mt][nt][0] + bf2f(pu.x) + bf2f(qu.x) + b4.x, 0.f));
      z.y = f2bf(fmaxf(acc[mt][nt][1] + bf2f(pu.y) + bf2f(qu.y) + b4.y, 0.f));
      z.z = f2bf(fmaxf(acc[mt][nt][2] + bf2f(pu.z) + bf2f(qu.z) + b4.z, 0.f));
      z.w = f2bf(fmaxf(acc[mt][nt][3] + bf2f(pu.w) + bf2f(qu.w) + b4.w, 0.f));
      *(ushort4*)(zbuf + er * ZS + cb * 2) = z;
    }
  }

  // ---- layer 1 MFMA, half B (channel blocks 4..7; bfr still live, acc reused)
  #pragma unroll
  for (int mt = 0; mt < 4; ++mt)
    #pragma unroll
    for (int nt = 0; nt < 2; ++nt) acc[mt][nt] = zero4();
  #pragma unroll
  for (int mt = 0; mt < 4; ++mt) {
    bf16x8 afr = *(const bf16x8*)(swzWea + ((mt + 4) * 64 + lane) * 8);
    #pragma unroll
    for (int nt = 0; nt < 2; ++nt)
      acc[mt][nt] = __builtin_amdgcn_mfma_f32_16x16x32_bf16(afr, bfr[nt], acc[mt][nt], 0, 0, 0);
  }

  // ---- prefetch Q blocks 4..7
  ushort4 qB[2][4];
  #pragma unroll
  for (int nt = 0; nt < 2; ++nt)
    #pragma unroll
    for (int mt = 0; mt < 4; ++mt)
      qB[nt][mt] = *(const ushort4*)(Q + dstO[nt] + (mt + 4) * 16 + quad * 4);

  // ---- epilogue 1, half B
  #pragma unroll
  for (int mt = 0; mt < 4; ++mt) {
    const int cb = (mt + 4) * 16 + quad * 4;
    const float4 b4 = *(const float4*)(bc1 + cb);
    #pragma unroll
    for (int nt = 0; nt < 2; ++nt) {
      ushort4 pu = pB[nt][mt];
      ushort4 qu = qB[nt][mt];
      int er = nt * 16 + l15;
      ushort4 z;
      z.x = f2bf(fmaxf(acc[mt][nt][0] + bf2f(pu.x) + bf2f(qu.x) + b4.x, 0.f));
      z.y = f2bf(fmaxf(acc[mt][nt][1] + bf2f(pu.y) + bf2f(qu.y) + b4.y, 0.f));
      z.z = f2bf(fmaxf(acc[mt][nt][2] + bf2f(pu.z) + bf2f(qu.z) + b4.z, 0.f));
      z.w = f2bf(fmaxf(acc[mt][nt][3] + bf2f(pu.w) + bf2f(qu.w) + b4.w, 0.f));
      *(ushort4*)(zbuf + er * ZS + cb * 2) = z;
    }
  }

  // ---- layer 2: z2^T = Wc2^T @ z1^T  (K=128, 64 out chans)
  f32x4 acc2[4][2];
  #pragma unroll
  for (int mt = 0; mt < 4; ++mt)
    #pragma unroll
    for (int nt = 0; nt < 2; ++nt) acc2[mt][nt] = zero4();

  #pragma unroll
  for (int c = 0; c < 4; ++c) {
    bf16x8 b2[2];
    #pragma unroll
    for (int nt = 0; nt < 2; ++nt)
      b2[nt] = *(const bf16x8*)(zbuf + (nt * 16 + l15) * ZS + (c * 32 + quad * 8) * 2);
    #pragma unroll
    for (int mt = 0; mt < 4; ++mt) {
      bf16x8 afr = *(const bf16x8*)(swzWc2 + ((mt * 4 + c) * 64 + lane) * 8);
      #pragma unroll
      for (int nt = 0; nt < 2; ++nt)
        acc2[mt][nt] = __builtin_amdgcn_mfma_f32_16x16x32_bf16(afr, b2[nt], acc2[mt][nt], 0, 0, 0);
    }
  }

  // ---- epilogue 2: z2 -> LDS rows (bf16, 64 chans, same stride; z1 reads done)
  #pragma unroll
  for (int mt = 0; mt < 4; ++mt) {
    const int cb = mt * 16 + quad * 4;
    const float4 b4 = *(const float4*)(bc2 + cb);
    #pragma unroll
    for (int nt = 0; nt < 2; ++nt) {
      int er = nt * 16 + l15;
      ushort4 z;
      z.x = f2bf(fmaxf(acc2[mt][nt][0] + b4.x, 0.f));
      z.y = f2bf(fmaxf(acc2[mt][nt][1] + b4.y, 0.f));
      z.z = f2bf(fmaxf(acc2[mt][nt][2] + b4.z, 0.f));
      z.w = f2bf(fmaxf(acc2[mt][nt][3] + b4.w, 0.f));
      *(ushort4*)(zbuf + er * ZS + cb * 2) = z;
    }
  }

  // ---- layer 3: lane pair per edge (half-wave split over 64 chans), sigmoid, scatter
  {
    int e = lane & 31, half = lane >> 5;
    float a3 = (half == 0) ? bc3[0] : 0.f;
    #pragma unroll
    for (int k2 = 0; k2 < 16; ++k2) {
      unsigned int u = *(const unsigned int*)(zbuf + e * ZS + half * 64 + k2 * 4);
      float v0 = __uint_as_float(u << 16);
      float v1 = __uint_as_float(u & 0xffff0000u);
      const float2 wv = *(const float2*)(Wc3 + half * 32 + 2 * k2);
      a3 += v0 * wv.x + v1 * wv.y;
    }
    a3 += __shfl_xor(a3, 32);
    if (half == 0) {
      int oe = csrDE[eBase + e].y;
      out[oe] = 1.f / (1.f + __expf(-a3));
    }
  }
}

// ---------------------------------------------------------------------------
extern "C" void kernel_launch(void* const* d_in, const int* in_sizes, int n_in,
                              void* d_out, int out_size, void* d_ws, size_t ws_size,
                              hipStream_t stream) {
  const float* x   = (const float*)d_in[0];
  const int*   ei  = (const int*)d_in[1];
  const float* ea  = (const float*)d_in[2];
  const float* Wl0 = (const float*)d_in[3];
  const float* Wr0 = (const float*)d_in[4];
  const float* b0  = (const float*)d_in[5];
  const float* Wl1 = (const float*)d_in[6];
  const float* Wr1 = (const float*)d_in[7];
  const float* b1  = (const float*)d_in[8];
  const float* Wc1 = (const float*)d_in[9];
  const float* bc1 = (const float*)d_in[10];
  const float* Wc2 = (const float*)d_in[11];
  const float* bc2 = (const float*)d_in[12];
  const float* Wc3 = (const float*)d_in[13];
  const float* bc3 = (const float*)d_in[14];
  float* out = (float*)d_out;

  char* ws = (char*)d_ws;
  int* degCnt    = (int*)(ws + 0);                            //    400,000 B
  int* rowPtr    = (int*)(ws + 400000);                       //    400,000 B
  int* cursor    = (int*)(ws + 800000);                       //    400,000 B
  int* blockSums = (int*)(ws + 1200000);                      //      2,048 B
  int* blockOff  = (int*)(ws + 1202048);                      //      2,048 B
  int* csrSrc    = (int*)(ws + 1204096);                      //  6,400,000 B
  int2* csrDE    = (int2*)(ws + 7604096);                     // 12,800,000 B
  __hip_bfloat16* bufB = (__hip_bfloat16*)(ws + 20404096);    // 25,600,000 B  msgB / P
  __hip_bfloat16* bufC = (__hip_bfloat16*)(ws + 46004096);    // 25,600,000 B  h0
  __hip_bfloat16* bufD = (__hip_bfloat16*)(ws + 71604096);    // 25,600,000 B  xb / Q
  __hip_bfloat16* swz  = (__hip_bfloat16*)(ws + 97204096);    //    221,184 B
  // total 97,425,280 B (unchanged from proven layout)
  __hip_bfloat16* msgB = bufB; __hip_bfloat16* Pb = bufB;   // P overwrites msgB in node_pq (safe: row-disjoint blocks)
  __hip_bfloat16* h0b  = bufC;
  __hip_bfloat16* xb   = bufD; __hip_bfloat16* Qb = bufD;   // xb dead after layer 0

  hipMemsetAsync(degCnt, 0, 400000, stream);
  prep_swizzle<<<432, 256, 0, stream>>>(Wl0, Wr0, Wl1, Wr1, Wc1, Wc2, swz);
  x_to_bf16<<<12500, 256, 0, stream>>>(x, xb);

  // CSR build (dst-sorted edge order; gathers + edge classifier)
  deg_count<<<NE / 256, 256, 0, stream>>>(ei, degCnt);
  scan_block_sums<<<NBLK, 256, 0, stream>>>(degCnt, blockSums);
  scan_partials<<<1, 512, 0, stream>>>(blockSums, blockOff);
  scan_write<<<NBLK, 256, 0, stream>>>(degCnt, blockOff, rowPtr, cursor);
  csr_fill<<<NE / 256, 256, 0, stream>>>(ei, cursor, csrSrc, csrDE);

  // layer 0
  gather_agg<<<NN / 16, 256, 0, stream>>>(xb, csrSrc, rowPtr, degCnt, msgB);
  node_gemm<<<NBLK, 256, 0, stream>>>(msgB, xb, swz, b0, h0b);

  // layer 1: gather, then fused node GEMM + P/Q GEMM (h1 never hits HBM)
  gather_agg<<<NN / 16, 256, 0, stream>>>(h0b, csrSrc, rowPtr, degCnt, msgB);
  node_pq_gemm<<<NBLK, 256, 0, stream>>>(msgB, h0b, swz + 32768, b1,
                                         swz + 65536, Pb, Qb);

  // per-edge MLP in CSR order
  edge_mlp<<<NE / 128, 256, 0, stream>>>(Pb, Qb, ea, csrSrc, csrDE,
                                         swz + 98304, swz + 102400,
                                         Wc3, bc1, bc2, bc3, out);
}

// Round 6
// 840.243 us; speedup vs baseline: 1.0678x; 1.0026x over previous
//
#include <hip/hip_runtime.h>
#include <hip/hip_bf16.h>
#include <math.h>

#define NN 100000
#define NE 1600000
#define NBLK 391   // ceil(NN/256)
#define ZS 296     // LDS row stride bytes (74 words, bank-shift 10 -> measured conflict-free)
// dims: D_IN = HID = 128, E_CH = 16

typedef __bf16 bf16x8 __attribute__((ext_vector_type(8)));
typedef float f32x4 __attribute__((ext_vector_type(4)));

union BF8 { bf16x8 v; unsigned short u[8]; };

static __device__ __forceinline__ unsigned short f2bf(float f) {
  unsigned int u = __float_as_uint(f);
  unsigned int r = u + 0x7fffu + ((u >> 16) & 1u);   // RNE
  return (unsigned short)(r >> 16);
}
static __device__ __forceinline__ float bf2f(unsigned short b) {
  return __uint_as_float((unsigned int)b << 16);
}
static __device__ __forceinline__ f32x4 zero4() {
  f32x4 z = {0.f, 0.f, 0.f, 0.f}; return z;
}
static __device__ __forceinline__ bf16x8 zerobf8() {
  BF8 t;
  #pragma unroll
  for (int j = 0; j < 8; ++j) t.u[j] = 0;
  return t.v;
}
static __device__ __forceinline__ bf16x8 cvt8(float4 v0, float4 v1, float s) {
  BF8 t;
  t.u[0]=f2bf(v0.x*s); t.u[1]=f2bf(v0.y*s); t.u[2]=f2bf(v0.z*s); t.u[3]=f2bf(v0.w*s);
  t.u[4]=f2bf(v1.x*s); t.u[5]=f2bf(v1.y*s); t.u[6]=f2bf(v1.z*s); t.u[7]=f2bf(v1.w*s);
  return t.v;
}

// ---------------------------------------------------------------------------
// Pre-swizzle weights into MFMA fragment order (bf16):
//   swz[((t*KC + c)*64 + lane)*8 + j] = W[k][n],  k = c*32 + (lane>>4)*8 + j,
//                                                 n = t*16 + (lane&15)
// element regions:
//   [0)      nodeW0 (Wl0|Wr0 stacked, K=256,N=128)   32768
//   [32768)  nodeW1                                   32768
//   [65536)  PQ0 = Wc1 rows   0..127 (K=128,N=128)    16384
//   [81920)  PQ1 = Wc1 rows 128..255 (K=128,N=128)    16384
//   [98304)  Wea = Wc1 rows 256..271 (K=16 pad 32)     4096
//   [102400) Wc2 (K=128,N=64)                          8192
// total 110592
__global__ void prep_swizzle(const float* __restrict__ Wl0, const float* __restrict__ Wr0,
                             const float* __restrict__ Wl1, const float* __restrict__ Wr1,
                             const float* __restrict__ Wc1, const float* __restrict__ Wc2,
                             __hip_bfloat16* __restrict__ swz) {
  int gid = blockIdx.x * 256 + threadIdx.x;
  if (gid >= 110592) return;
  int id = gid;
  const float* A; const float* B = nullptr; int KC, Nc, Ksrc;
  if (id < 32768)        { KC = 8; Nc = 128; Ksrc = 256; A = Wl0; B = Wr0; }
  else if (id < 65536)   { id -= 32768; KC = 8; Nc = 128; Ksrc = 256; A = Wl1; B = Wr1; }
  else if (id < 81920)   { id -= 65536; KC = 4; Nc = 128; Ksrc = 128; A = Wc1; }
  else if (id < 98304)   { id -= 81920; KC = 4; Nc = 128; Ksrc = 128; A = Wc1 + 128 * 128; }
  else if (id < 102400)  { id -= 98304; KC = 1; Nc = 128; Ksrc = 16;  A = Wc1 + 256 * 128; }
  else                   { id -= 102400; KC = 4; Nc = 64;  Ksrc = 128; A = Wc2; }
  int j = id & 7, lane = (id >> 3) & 63, rest = id >> 9;
  int c = rest % KC, t = rest / KC;
  int k = c * 32 + (lane >> 4) * 8 + j;
  int n = t * 16 + (lane & 15);
  float v = 0.f;
  if (k < Ksrc) {
    if (B && k >= 128) v = B[(k - 128) * Nc + n];
    else               v = A[k * Nc + n];
  }
  unsigned short* o = (unsigned short*)swz;
  o[gid] = f2bf(v);
}

// ---------------------------------------------------------------------------
// x (fp32) -> bf16, vectorized
__global__ void x_to_bf16(const float* __restrict__ x, __hip_bfloat16* __restrict__ xb) {
  int i = blockIdx.x * 256 + threadIdx.x;     // one float4 per thread
  float4 v = ((const float4*)x)[i];
  ushort4 p;
  p.x = f2bf(v.x); p.y = f2bf(v.y); p.z = f2bf(v.z); p.w = f2bf(v.w);
  ((ushort4*)xb)[i] = p;
}

// ---------------------------------------------------------------------------
// CSR build: count degrees, scan, fill (src + packed (dst,eid))
__global__ void deg_count(const int* __restrict__ ei, int* __restrict__ degCnt) {
  int e = blockIdx.x * 256 + threadIdx.x;
  atomicAdd(&degCnt[ei[NE + e]], 1);
}

__global__ void scan_block_sums(const int* __restrict__ degCnt, int* __restrict__ blockSums) {
  __shared__ int red[4];
  int i = blockIdx.x * 256 + threadIdx.x;
  int v = (i < NN) ? degCnt[i] : 0;
  #pragma unroll
  for (int off = 32; off; off >>= 1) v += __shfl_down(v, off, 64);
  if ((threadIdx.x & 63) == 0) red[threadIdx.x >> 6] = v;
  __syncthreads();
  if (threadIdx.x == 0) blockSums[blockIdx.x] = red[0] + red[1] + red[2] + red[3];
}

__global__ void scan_partials(const int* __restrict__ blockSums, int* __restrict__ blockOff) {
  __shared__ int lds[512];
  int t = threadIdx.x;
  int v = (t < NBLK) ? blockSums[t] : 0;
  lds[t] = v; __syncthreads();
  #pragma unroll
  for (int off = 1; off < 512; off <<= 1) {
    int a = (t >= off) ? lds[t - off] : 0;
    __syncthreads();
    lds[t] += a;
    __syncthreads();
  }
  if (t < NBLK) blockOff[t] = lds[t] - v;   // exclusive
}

__global__ void scan_write(const int* __restrict__ degCnt, const int* __restrict__ blockOff,
                           int* __restrict__ rowPtr, int* __restrict__ cursor) {
  __shared__ int lds[256];
  int t = threadIdx.x;
  int i = blockIdx.x * 256 + t;
  int v = (i < NN) ? degCnt[i] : 0;
  lds[t] = v; __syncthreads();
  #pragma unroll
  for (int off = 1; off < 256; off <<= 1) {
    int a = (t >= off) ? lds[t - off] : 0;
    __syncthreads();
    lds[t] += a;
    __syncthreads();
  }
  if (i < NN) {
    int excl = blockOff[blockIdx.x] + lds[t] - v;
    rowPtr[i] = excl;
    cursor[i] = excl;
  }
}

__global__ void csr_fill(const int* __restrict__ ei, int* __restrict__ cursor,
                         int* __restrict__ csrSrc, int2* __restrict__ csrDE) {
  int e = blockIdx.x * 256 + threadIdx.x;
  int s = ei[e], d = ei[NE + e];
  int idx = atomicAdd(&cursor[d], 1);
  csrSrc[idx] = s;
  csrDE[idx] = make_int2(d, e);
}

// ---------------------------------------------------------------------------
// gather-mean: msgOut[n] = mean over neighbors s of feat[s]  (bf16 in/out)
// 16 lanes per node (16B each = full 256B row), 16 nodes/block.
// Unroll-8 with explicit index-batch -> load-batch: 8 random feat loads in flight
// per lane-group (latency-bound random gather; TLP already maxed, this adds ILP).
__global__ __launch_bounds__(256, 8)
void gather_agg(const __hip_bfloat16* __restrict__ xb,
                const int* __restrict__ csrSrc, const int* __restrict__ rowPtr,
                const int* __restrict__ degCnt, __hip_bfloat16* __restrict__ msgOut) {
  int g = threadIdx.x >> 4, c16 = threadIdx.x & 15;
  int n = blockIdx.x * 16 + g;             // grid 6250 x 16 = 100000 exact
  int rp = rowPtr[n], dg = degCnt[n];
  float a[8];
  #pragma unroll
  for (int j = 0; j < 8; ++j) a[j] = 0.f;
  for (int i = 0; i < dg; i += 8) {
    int sidx[8];
    #pragma unroll
    for (int k = 0; k < 8; ++k) {
      int ii = i + k;
      sidx[k] = csrSrc[rp + (ii < dg ? ii : dg - 1)];
    }
    uint4 u[8];
    #pragma unroll
    for (int k = 0; k < 8; ++k)
      u[k] = *(const uint4*)((const unsigned short*)xb + (size_t)sidx[k] * 128 + c16 * 8);
    #pragma unroll
    for (int k = 0; k < 8; ++k) {
      if (i + k < dg) {
        a[0] += bf2f((unsigned short)(u[k].x & 0xffff)); a[1] += bf2f((unsigned short)(u[k].x >> 16));
        a[2] += bf2f((unsigned short)(u[k].y & 0xffff)); a[3] += bf2f((unsigned short)(u[k].y >> 16));
        a[4] += bf2f((unsigned short)(u[k].z & 0xffff)); a[5] += bf2f((unsigned short)(u[k].z >> 16));
        a[6] += bf2f((unsigned short)(u[k].w & 0xffff)); a[7] += bf2f((unsigned short)(u[k].w >> 16));
      }
    }
  }
  float r = 1.f / fmaxf((float)dg, 1.f);
  uint4 p;
  p.x = (unsigned)f2bf(a[0] * r) | ((unsigned)f2bf(a[1] * r) << 16);
  p.y = (unsigned)f2bf(a[2] * r) | ((unsigned)f2bf(a[3] * r) << 16);
  p.z = (unsigned)f2bf(a[4] * r) | ((unsigned)f2bf(a[5] * r) << 16);
  p.w = (unsigned)f2bf(a[6] * r) | ((unsigned)f2bf(a[7] * r) << 16);
  *(uint4*)((unsigned short*)msgOut + (size_t)n * 128 + c16 * 8) = p;
}

// ---------------------------------------------------------------------------
// node GEMM (layer 0): h[n] = relu([mean | self[n]] @ [Wl;Wr] + b)   -> bf16 out
__global__ __launch_bounds__(256, 2)
void node_gemm(const __hip_bfloat16* __restrict__ msgB,
               const __hip_bfloat16* __restrict__ selfB16,
               const __hip_bfloat16* __restrict__ swzW, const float* __restrict__ bias,
               __hip_bfloat16* __restrict__ hOut) {
  const int tid = threadIdx.x, w = tid >> 6, lane = tid & 63;
  const int l15 = lane & 15, quad = lane >> 4;
  const int nBase = blockIdx.x * 256 + w * 64;

  int row[4];
  #pragma unroll
  for (int t = 0; t < 4; ++t) {
    int n = nBase + t * 16 + l15;
    if (n > NN - 1) n = NN - 1;
    row[t] = n;
  }

  f32x4 acc[8][4];
  #pragma unroll
  for (int mt = 0; mt < 8; ++mt)
    #pragma unroll
    for (int nt = 0; nt < 4; ++nt) acc[mt][nt] = zero4();

  #pragma unroll
  for (int c = 0; c < 8; ++c) {
    bf16x8 bfr[4];
    if (c < 4) {
      #pragma unroll
      for (int nt = 0; nt < 4; ++nt)
        bfr[nt] = *(const bf16x8*)(msgB + (size_t)row[nt] * 128 + c * 32 + quad * 8);
    } else {
      #pragma unroll
      for (int nt = 0; nt < 4; ++nt)
        bfr[nt] = *(const bf16x8*)(selfB16 + (size_t)row[nt] * 128 + (c - 4) * 32 + quad * 8);
    }
    bf16x8 afr[8];
    #pragma unroll
    for (int mt = 0; mt < 8; ++mt)
      afr[mt] = *(const bf16x8*)(swzW + ((mt * 8 + c) * 64 + lane) * 8);
    #pragma unroll
    for (int mt = 0; mt < 8; ++mt)
      #pragma unroll
      for (int nt = 0; nt < 4; ++nt)
        acc[mt][nt] = __builtin_amdgcn_mfma_f32_16x16x32_bf16(afr[mt], bfr[nt], acc[mt][nt], 0, 0, 0);
  }

  #pragma unroll
  for (int mt = 0; mt < 8; ++mt) {
    const float4 b4 = *(const float4*)(bias + mt * 16 + quad * 4);
    #pragma unroll
    for (int nt = 0; nt < 4; ++nt) {
      int n = nBase + nt * 16 + l15;
      if (n < NN) {
        ushort4 p;
        p.x = f2bf(fmaxf(acc[mt][nt][0] + b4.x, 0.f));
        p.y = f2bf(fmaxf(acc[mt][nt][1] + b4.y, 0.f));
        p.z = f2bf(fmaxf(acc[mt][nt][2] + b4.z, 0.f));
        p.w = f2bf(fmaxf(acc[mt][nt][3] + b4.w, 0.f));
        *(ushort4*)(hOut + (size_t)n * 128 + mt * 16 + quad * 4) = p;
      }
    }
  }
}

// ---------------------------------------------------------------------------
// node GEMM + P/Q GEMM fused (layer 1): dense->dense fusion only (no gather, no
// barrier, no occupancy change). h1 = relu([mean|self]W1+b1) -> wave-private LDS ->
// P = Wc1a^T h1, Q = Wc1b^T h1. Eliminates the h1 HBM round-trip (51.2 MB) and the
// separate pq_gemm launch.
// NOTE: Pout may alias msgB — each block reads only its own 256 msgB rows (phase A)
// before writing the same rows as P (phase B); blocks are row-disjoint.
__global__ __launch_bounds__(256, 2)
void node_pq_gemm(const __hip_bfloat16* __restrict__ msgB,
                  const __hip_bfloat16* __restrict__ selfB16,
                  const __hip_bfloat16* __restrict__ swzW, const float* __restrict__ bias,
                  const __hip_bfloat16* __restrict__ swzPQ,
                  __hip_bfloat16* __restrict__ Pout, __hip_bfloat16* __restrict__ Qout) {
  __shared__ __align__(16) char hLds[4 * 64 * ZS];   // 75776 B -> 2 blocks/CU
  const int tid = threadIdx.x, w = tid >> 6, lane = tid & 63;
  const int l15 = lane & 15, quad = lane >> 4;
  const int nBase = blockIdx.x * 256 + w * 64;
  char* hbuf = hLds + w * (64 * ZS);

  int row[4];
  #pragma unroll
  for (int t = 0; t < 4; ++t) {
    int n = nBase + t * 16 + l15;
    if (n > NN - 1) n = NN - 1;
    row[t] = n;
  }

  // ---- phase A: node GEMM, relu -> hbuf (LDS, bf16, stride ZS)
  {
    f32x4 acc[8][4];
    #pragma unroll
    for (int mt = 0; mt < 8; ++mt)
      #pragma unroll
      for (int nt = 0; nt < 4; ++nt) acc[mt][nt] = zero4();

    #pragma unroll
    for (int c = 0; c < 8; ++c) {
      bf16x8 bfr[4];
      if (c < 4) {
        #pragma unroll
        for (int nt = 0; nt < 4; ++nt)
          bfr[nt] = *(const bf16x8*)(msgB + (size_t)row[nt] * 128 + c * 32 + quad * 8);
      } else {
        #pragma unroll
        for (int nt = 0; nt < 4; ++nt)
          bfr[nt] = *(const bf16x8*)(selfB16 + (size_t)row[nt] * 128 + (c - 4) * 32 + quad * 8);
      }
      bf16x8 afr[8];
      #pragma unroll
      for (int mt = 0; mt < 8; ++mt)
        afr[mt] = *(const bf16x8*)(swzW + ((mt * 8 + c) * 64 + lane) * 8);
      #pragma unroll
      for (int mt = 0; mt < 8; ++mt)
        #pragma unroll
        for (int nt = 0; nt < 4; ++nt)
          acc[mt][nt] = __builtin_amdgcn_mfma_f32_16x16x32_bf16(afr[mt], bfr[nt], acc[mt][nt], 0, 0, 0);
    }

    #pragma unroll
    for (int mt = 0; mt < 8; ++mt) {
      const int cb = mt * 16 + quad * 4;
      const float4 b4 = *(const float4*)(bias + cb);
      #pragma unroll
      for (int nt = 0; nt < 4; ++nt) {
        ushort4 p;
        p.x = f2bf(fmaxf(acc[mt][nt][0] + b4.x, 0.f));
        p.y = f2bf(fmaxf(acc[mt][nt][1] + b4.y, 0.f));
        p.z = f2bf(fmaxf(acc[mt][nt][2] + b4.z, 0.f));
        p.w = f2bf(fmaxf(acc[mt][nt][3] + b4.w, 0.f));
        *(ushort4*)(hbuf + (nt * 16 + l15) * ZS + cb * 2) = p;
      }
    }
  }

  // ---- phase B: P (hf=0) then Q (hf=1), K=128 from hbuf (wave-private: no barrier)
  for (int hf = 0; hf < 2; ++hf) {
    const __hip_bfloat16* swzH = swzPQ + hf * 16384;
    __hip_bfloat16* outp = hf ? Qout : Pout;
    f32x4 acc2[8][4];
    #pragma unroll
    for (int mt = 0; mt < 8; ++mt)
      #pragma unroll
      for (int nt = 0; nt < 4; ++nt) acc2[mt][nt] = zero4();

    #pragma unroll
    for (int c = 0; c < 4; ++c) {
      bf16x8 bfr[4];
      #pragma unroll
      for (int nt = 0; nt < 4; ++nt)
        bfr[nt] = *(const bf16x8*)(hbuf + (nt * 16 + l15) * ZS + (c * 32 + quad * 8) * 2);
      bf16x8 afr[8];
      #pragma unroll
      for (int mt = 0; mt < 8; ++mt)
        afr[mt] = *(const bf16x8*)(swzH + ((mt * 4 + c) * 64 + lane) * 8);
      #pragma unroll
      for (int mt = 0; mt < 8; ++mt)
        #pragma unroll
        for (int nt = 0; nt < 4; ++nt)
          acc2[mt][nt] = __builtin_amdgcn_mfma_f32_16x16x32_bf16(afr[mt], bfr[nt], acc2[mt][nt], 0, 0, 0);
    }

    #pragma unroll
    for (int mt = 0; mt < 8; ++mt) {
      #pragma unroll
      for (int nt = 0; nt < 4; ++nt) {
        int n = nBase + nt * 16 + l15;
        if (n < NN) {
          ushort4 p;
          p.x = f2bf(acc2[mt][nt][0]);
          p.y = f2bf(acc2[mt][nt][1]);
          p.z = f2bf(acc2[mt][nt][2]);
          p.w = f2bf(acc2[mt][nt][3]);
          *(ushort4*)(outp + (size_t)n * 128 + mt * 16 + quad * 4) = p;
        }
      }
    }
  }
}

// ---------------------------------------------------------------------------
// edge MLP (CSR order): z1 = relu(P[src]+Q[dst]+Wea^T ea+bc1); z2 = relu(Wc2^T z1+bc2);
// out[eid] = sigmoid(Wc3^T z2 + bc3).
// R5 change: 16 edges/wave (was 32) -> LDS/block 37888->18944 B -> 8 blocks/CU
// -> 32 waves/CU (was 13.6). Latency-bound kernel (occ 42%, all pipes <35%,
// BW 1.6 TB/s << any ceiling): double the TLP. Same instructions per edge.
// 4 waves x 16 edges/wave, per-wave private LDS z-buffer, no barriers.
__global__ __launch_bounds__(256, 8)
void edge_mlp(const __hip_bfloat16* __restrict__ P, const __hip_bfloat16* __restrict__ Q,
              const float* __restrict__ ea,
              const int* __restrict__ csrSrc, const int2* __restrict__ csrDE,
              const __hip_bfloat16* __restrict__ swzWea, const __hip_bfloat16* __restrict__ swzWc2,
              const float* __restrict__ Wc3, const float* __restrict__ bc1,
              const float* __restrict__ bc2, const float* __restrict__ bc3,
              float* __restrict__ out) {
  __shared__ char lds[4 * 16 * ZS];   // 18944 B -> 8 blocks/CU
  const int tid = threadIdx.x, w = tid >> 6, lane = tid & 63;
  const int l15 = lane & 15, quad = lane >> 4;
  const int eBase = blockIdx.x * 64 + w * 16;
  char* zbuf = lds + w * (16 * ZS);

  int srcO, dstO, eid;
  {
    int p = eBase + l15;
    srcO = csrSrc[p] * 128;
    int2 de = csrDE[p];
    dstO = de.x * 128;
    eid = de.y;
  }

  // ---- prefetch P channel blocks 0..3 (random gather, L3 latency) ASAP
  ushort4 pA[4];
  #pragma unroll
  for (int mt = 0; mt < 4; ++mt)
    pA[mt] = *(const ushort4*)(P + srcO + mt * 16 + quad * 4);

  // ---- ea -> bf16 B fragment (K=16 zero-padded to 32)
  bf16x8 bfr;
  if (quad < 2) {
    const float4* pe = (const float4*)(ea + (size_t)eid * 16 + quad * 8);
    bfr = cvt8(pe[0], pe[1], 1.f);
  } else {
    bfr = zerobf8();
  }

  // ---- layer 1 MFMA, half A (channel blocks 0..3)
  f32x4 acc[4];
  #pragma unroll
  for (int mt = 0; mt < 4; ++mt) acc[mt] = zero4();
  #pragma unroll
  for (int mt = 0; mt < 4; ++mt) {
    bf16x8 afr = *(const bf16x8*)(swzWea + (mt * 64 + lane) * 8);
    acc[mt] = __builtin_amdgcn_mfma_f32_16x16x32_bf16(afr, bfr, acc[mt], 0, 0, 0);
  }

  // ---- prefetch P blocks 4..7 and Q blocks 0..3 (consumed next phase)
  ushort4 pB[4], qA[4];
  #pragma unroll
  for (int mt = 0; mt < 4; ++mt)
    pB[mt] = *(const ushort4*)(P + srcO + (mt + 4) * 16 + quad * 4);
  #pragma unroll
  for (int mt = 0; mt < 4; ++mt)
    qA[mt] = *(const ushort4*)(Q + dstO + mt * 16 + quad * 4);

  // ---- epilogue 1, half A: z1 = relu(acc + P + Q + bc1) -> LDS (bf16, stride ZS)
  #pragma unroll
  for (int mt = 0; mt < 4; ++mt) {
    const int cb = mt * 16 + quad * 4;
    const float4 b4 = *(const float4*)(bc1 + cb);
    ushort4 pu = pA[mt];
    ushort4 qu = qA[mt];
    ushort4 z;
    z.x = f2bf(fmaxf(acc[mt][0] + bf2f(pu.x) + bf2f(qu.x) + b4.x, 0.f));
    z.y = f2bf(fmaxf(acc[mt][1] + bf2f(pu.y) + bf2f(qu.y) + b4.y, 0.f));
    z.z = f2bf(fmaxf(acc[mt][2] + bf2f(pu.z) + bf2f(qu.z) + b4.z, 0.f));
    z.w = f2bf(fmaxf(acc[mt][3] + bf2f(pu.w) + bf2f(qu.w) + b4.w, 0.f));
    *(ushort4*)(zbuf + l15 * ZS + cb * 2) = z;
  }

  // ---- layer 1 MFMA, half B (channel blocks 4..7; bfr still live, acc reused)
  #pragma unroll
  for (int mt = 0; mt < 4; ++mt) acc[mt] = zero4();
  #pragma unroll
  for (int mt = 0; mt < 4; ++mt) {
    bf16x8 afr = *(const bf16x8*)(swzWea + ((mt + 4) * 64 + lane) * 8);
    acc[mt] = __builtin_amdgcn_mfma_f32_16x16x32_bf16(afr, bfr, acc[mt], 0, 0, 0);
  }

  // ---- prefetch Q blocks 4..7
  ushort4 qB[4];
  #pragma unroll
  for (int mt = 0; mt < 4; ++mt)
    qB[mt] = *(const ushort4*)(Q + dstO + (mt + 4) * 16 + quad * 4);

  // ---- epilogue 1, half B
  #pragma unroll
  for (int mt = 0; mt < 4; ++mt) {
    const int cb = (mt + 4) * 16 + quad * 4;
    const float4 b4 = *(const float4*)(bc1 + cb);
    ushort4 pu = pB[mt];
    ushort4 qu = qB[mt];
    ushort4 z;
    z.x = f2bf(fmaxf(acc[mt][0] + bf2f(pu.x) + bf2f(qu.x) + b4.x, 0.f));
    z.y = f2bf(fmaxf(acc[mt][1] + bf2f(pu.y) + bf2f(qu.y) + b4.y, 0.f));
    z.z = f2bf(fmaxf(acc[mt][2] + bf2f(pu.z) + bf2f(qu.z) + b4.z, 0.f));
    z.w = f2bf(fmaxf(acc[mt][3] + bf2f(pu.w) + bf2f(qu.w) + b4.w, 0.f));
    *(ushort4*)(zbuf + l15 * ZS + cb * 2) = z;
  }

  // ---- layer 2: z2^T = Wc2^T @ z1^T  (K=128, 64 out chans)
  f32x4 acc2[4];
  #pragma unroll
  for (int mt = 0; mt < 4; ++mt) acc2[mt] = zero4();

  #pragma unroll
  for (int c = 0; c < 4; ++c) {
    bf16x8 b2 = *(const bf16x8*)(zbuf + l15 * ZS + (c * 32 + quad * 8) * 2);
    #pragma unroll
    for (int mt = 0; mt < 4; ++mt) {
      bf16x8 afr = *(const bf16x8*)(swzWc2 + ((mt * 4 + c) * 64 + lane) * 8);
      acc2[mt] = __builtin_amdgcn_mfma_f32_16x16x32_bf16(afr, b2, acc2[mt], 0, 0, 0);
    }
  }

  // ---- epilogue 2: z2 -> LDS rows (bf16, 64 chans, same stride; z1 reads done)
  #pragma unroll
  for (int mt = 0; mt < 4; ++mt) {
    const int cb = mt * 16 + quad * 4;
    const float4 b4 = *(const float4*)(bc2 + cb);
    ushort4 z;
    z.x = f2bf(fmaxf(acc2[mt][0] + b4.x, 0.f));
    z.y = f2bf(fmaxf(acc2[mt][1] + b4.y, 0.f));
    z.z = f2bf(fmaxf(acc2[mt][2] + b4.z, 0.f));
    z.w = f2bf(fmaxf(acc2[mt][3] + b4.w, 0.f));
    *(ushort4*)(zbuf + l15 * ZS + cb * 2) = z;
  }

  // ---- layer 3: 4 lanes per edge (16 chans each), 2-step shfl reduce, sigmoid,
  //      scatter (CSR order, eid from csrDE)
  {
    int e = lane & 15, seg = lane >> 4;
    float a3 = (seg == 0) ? bc3[0] : 0.f;
    #pragma unroll
    for (int k2 = 0; k2 < 8; ++k2) {
      unsigned int u = *(const unsigned int*)(zbuf + e * ZS + seg * 32 + k2 * 4);
      float v0 = __uint_as_float(u << 16);
      float v1 = __uint_as_float(u & 0xffff0000u);
      const float2 wv = *(const float2*)(Wc3 + seg * 16 + 2 * k2);
      a3 += v0 * wv.x + v1 * wv.y;
    }
    a3 += __shfl_xor(a3, 16);
    a3 += __shfl_xor(a3, 32);
    if (seg == 0) {
      int oe = csrDE[eBase + e].y;
      out[oe] = 1.f / (1.f + __expf(-a3));
    }
  }
}

// ---------------------------------------------------------------------------
extern "C" void kernel_launch(void* const* d_in, const int* in_sizes, int n_in,
                              void* d_out, int out_size, void* d_ws, size_t ws_size,
                              hipStream_t stream) {
  const float* x   = (const float*)d_in[0];
  const int*   ei  = (const int*)d_in[1];
  const float* ea  = (const float*)d_in[2];
  const float* Wl0 = (const float*)d_in[3];
  const float* Wr0 = (const float*)d_in[4];
  const float* b0  = (const float*)d_in[5];
  const float* Wl1 = (const float*)d_in[6];
  const float* Wr1 = (const float*)d_in[7];
  const float* b1  = (const float*)d_in[8];
  const float* Wc1 = (const float*)d_in[9];
  const float* bc1 = (const float*)d_in[10];
  const float* Wc2 = (const float*)d_in[11];
  const float* bc2 = (const float*)d_in[12];
  const float* Wc3 = (const float*)d_in[13];
  const float* bc3 = (const float*)d_in[14];
  float* out = (float*)d_out;

  char* ws = (char*)d_ws;
  int* degCnt    = (int*)(ws + 0);                            //    400,000 B
  int* rowPtr    = (int*)(ws + 400000);                       //    400,000 B
  int* cursor    = (int*)(ws + 800000);                       //    400,000 B
  int* blockSums = (int*)(ws + 1200000);                      //      2,048 B
  int* blockOff  = (int*)(ws + 1202048);                      //      2,048 B
  int* csrSrc    = (int*)(ws + 1204096);                      //  6,400,000 B
  int2* csrDE    = (int2*)(ws + 7604096);                     // 12,800,000 B
  __hip_bfloat16* bufB = (__hip_bfloat16*)(ws + 20404096);    // 25,600,000 B  msgB / P
  __hip_bfloat16* bufC = (__hip_bfloat16*)(ws + 46004096);    // 25,600,000 B  h0
  __hip_bfloat16* bufD = (__hip_bfloat16*)(ws + 71604096);    // 25,600,000 B  xb / Q
  __hip_bfloat16* swz  = (__hip_bfloat16*)(ws + 97204096);    //    221,184 B
  // total 97,425,280 B (unchanged from proven layout)
  __hip_bfloat16* msgB = bufB; __hip_bfloat16* Pb = bufB;   // P overwrites msgB in node_pq (safe: row-disjoint blocks)
  __hip_bfloat16* h0b  = bufC;
  __hip_bfloat16* xb   = bufD; __hip_bfloat16* Qb = bufD;   // xb dead after layer 0

  hipMemsetAsync(degCnt, 0, 400000, stream);
  prep_swizzle<<<432, 256, 0, stream>>>(Wl0, Wr0, Wl1, Wr1, Wc1, Wc2, swz);
  x_to_bf16<<<12500, 256, 0, stream>>>(x, xb);

  // CSR build (dst-sorted edge order; gathers + edge classifier)
  deg_count<<<NE / 256, 256, 0, stream>>>(ei, degCnt);
  scan_block_sums<<<NBLK, 256, 0, stream>>>(degCnt, blockSums);
  scan_partials<<<1, 512, 0, stream>>>(blockSums, blockOff);
  scan_write<<<NBLK, 256, 0, stream>>>(degCnt, blockOff, rowPtr, cursor);
  csr_fill<<<NE / 256, 256, 0, stream>>>(ei, cursor, csrSrc, csrDE);

  // layer 0
  gather_agg<<<NN / 16, 256, 0, stream>>>(xb, csrSrc, rowPtr, degCnt, msgB);
  node_gemm<<<NBLK, 256, 0, stream>>>(msgB, xb, swz, b0, h0b);

  // layer 1: gather, then fused node GEMM + P/Q GEMM (h1 never hits HBM)
  gather_agg<<<NN / 16, 256, 0, stream>>>(h0b, csrSrc, rowPtr, degCnt, msgB);
  node_pq_gemm<<<NBLK, 256, 0, stream>>>(msgB, h0b, swz + 32768, b1,
                                         swz + 65536, Pb, Qb);

  // per-edge MLP in CSR order (16 edges/wave -> 8 blocks/CU)
  edge_mlp<<<NE / 64, 256, 0, stream>>>(Pb, Qb, ea, csrSrc, csrDE,
                                        swz + 98304, swz + 102400,
                                        Wc3, bc1, bc2, bc3, out);
}